// Round 7
// baseline (482.008 us; speedup 1.0000x reference)
//
#include <hip/hip_runtime.h>

#define SS 2048
#define DD 1024
#define HH 16
#define DHD 64
#define HSN (HH * SS)  // 32768
#define LOG2E 1.44269504088896340736f

typedef __bf16 bf16x8 __attribute__((ext_vector_type(8)));
typedef __bf16 bf16x4 __attribute__((ext_vector_type(4)));
typedef float f32x4 __attribute__((ext_vector_type(4)));
typedef unsigned int u32;
typedef unsigned long long u64;

__device__ __forceinline__ void glds16(const void* g, void* l) {
  __builtin_amdgcn_global_load_lds(
      (const __attribute__((address_space(1))) u32*)(const u32*)g,
      (__attribute__((address_space(3))) u32*)(u32*)l, 16, 0, 0);
}

// ------ fused fp32 -> bf16 converts (x, Wq, Wk, Wv, Wo) + mask bit-pack (z==5) ----
__global__ __launch_bounds__(256) void cvt_all_kernel(const float* __restrict__ x,
                                                      const float* __restrict__ Wq,
                                                      const float* __restrict__ Wk,
                                                      const float* __restrict__ Wv,
                                                      const float* __restrict__ Wo,
                                                      __bf16* xb, __bf16* Wqb, __bf16* Wkb,
                                                      __bf16* Wvb, __bf16* Wob,
                                                      const int* __restrict__ mask,
                                                      u64* __restrict__ mp) {
  const int z = blockIdx.z;
  if (z == 5) {  // mask bit-pack: 16 MB int32 -> 512 KB u64 (8 words per wave)
    const int wid = (blockIdx.x * 256 + threadIdx.x) >> 6;  // 8192 waves
    const int lane = threadIdx.x & 63;
#pragma unroll
    for (int w = 0; w < 8; ++w) {
      const long word = (long)wid * 8 + w;
      const u64 b = __ballot(mask[word * 64 + lane] != 0);
      if (lane == 0) mp[word] = b;
    }
    return;
  }
  const int n4 = (z == 0 ? SS * DD : DD * DD) / 4;
  const int i = blockIdx.x * 256 + threadIdx.x;
  if (i >= n4) return;
  const float* in = z == 0 ? x : (z == 1 ? Wq : (z == 2 ? Wk : (z == 3 ? Wv : Wo)));
  __bf16* out = z == 0 ? xb : (z == 1 ? Wqb : (z == 2 ? Wkb : (z == 3 ? Wvb : Wob)));
  const float4 v = ((const float4*)in)[i];
  bf16x4 r;
  r[0] = (__bf16)v.x; r[1] = (__bf16)v.y; r[2] = (__bf16)v.z; r[3] = (__bf16)v.w;
  *(bf16x4*)&out[(long)i * 4] = r;
}

// ---------------- NT GEMM body (m97 single-buffer, proven structure) ----
// C = A[M,K] * B[N,K]^T. BM in {64,128}, BN=128, BK=32.
// mode 0: bf16 out; mode 1: f32 out; mode 2: bf16 transposed out (V^T);
// mode 3: f32 out with fused residual add (Cout = acc + Xres).
template <int BM>
__device__ __forceinline__ void gemm_body(const __bf16* __restrict__ A,
                                          const __bf16* __restrict__ B,
                                          void* __restrict__ Cout, float scale, int mode,
                                          int bx, int by,
                                          const float* __restrict__ Xres = nullptr) {
  constexpr int MR = BM / 32;  // acc rows per wave
  __shared__ alignas(16) __bf16 As[BM * 32];
  __shared__ alignas(16) __bf16 Bs[128 * 32];
  const int tid = threadIdx.x;
  const int lane = tid & 63;
  const int wave = tid >> 6;
  const long m0 = (long)by * BM;
  const long n0 = (long)bx * 128;
  const int wm = (wave >> 1) * (BM / 2);
  const int wn = (wave & 1) * 64;
  const int g = lane >> 4, r16 = lane & 15;
  const int srow = tid >> 2, sseg = (tid & 3) * 8;

  f32x4 acc[MR][4] = {};

  for (int k0 = 0; k0 < DD; k0 += 32) {
#pragma unroll
    for (int it = 0; it < 2; ++it) {
      const int row = srow + it * 64;
      glds16(&B[(n0 + row) * DD + k0 + sseg], &Bs[row * 32 + sseg]);
    }
#pragma unroll
    for (int it = 0; it < BM / 64; ++it) {
      const int row = srow + it * 64;
      glds16(&A[(m0 + row) * DD + k0 + sseg], &As[row * 32 + sseg]);
    }
    __syncthreads();
    bf16x8 af[MR], bfr[4];
#pragma unroll
    for (int r = 0; r < MR; ++r) af[r] = *(const bf16x8*)&As[(wm + r * 16 + r16) * 32 + g * 8];
#pragma unroll
    for (int c = 0; c < 4; ++c) bfr[c] = *(const bf16x8*)&Bs[(wn + c * 16 + r16) * 32 + g * 8];
#pragma unroll
    for (int r = 0; r < MR; ++r)
#pragma unroll
      for (int c = 0; c < 4; ++c)
        acc[r][c] = __builtin_amdgcn_mfma_f32_16x16x32_bf16(af[r], bfr[c], acc[r][c], 0, 0, 0);
    __syncthreads();
  }

  if (mode == 2) {  // transposed bf16 store (V^T): 8B contiguous over i (rows)
#pragma unroll
    for (int r = 0; r < MR; ++r)
#pragma unroll
      for (int c = 0; c < 4; ++c) {
        const long row0 = m0 + wm + r * 16 + g * 4;
        const long col = n0 + wn + c * 16 + r16;
        bf16x4 rv;
#pragma unroll
        for (int i = 0; i < 4; ++i) rv[i] = (__bf16)(acc[r][c][i] * scale);
        *(bf16x4*)&((__bf16*)Cout)[col * SS + row0] = rv;
      }
  } else {
#pragma unroll
    for (int r = 0; r < MR; ++r)
#pragma unroll
      for (int c = 0; c < 4; ++c)
#pragma unroll
        for (int i = 0; i < 4; ++i) {
          const long row = m0 + wm + r * 16 + g * 4 + i;
          const long col = n0 + wn + c * 16 + r16;
          float v = acc[r][c][i] * scale;
          if (mode == 3) v += Xres[row * DD + col];
          if (mode != 0) ((float*)Cout)[row * DD + col] = v;
          else           ((__bf16*)Cout)[row * DD + col] = (__bf16)v;
        }
  }
}

// QKV projections: BM=64 -> grid (8,32,3) = 768 blocks = 3/CU.
__global__ __launch_bounds__(256) void gemm_qkv(const __bf16* __restrict__ A,
                                                const __bf16* __restrict__ B0,
                                                const __bf16* __restrict__ B1,
                                                const __bf16* __restrict__ B2,
                                                __bf16* C0, __bf16* C1, __bf16* C2,
                                                float s0) {
  const int z = blockIdx.z;
  const __bf16* B = z == 0 ? B0 : (z == 1 ? B1 : B2);
  __bf16* C = z == 0 ? C0 : (z == 1 ? C1 : C2);
  // z==2 writes V^T directly (mode 2) -> no separate transpose kernel
  gemm_body<64>(A, B, C, z == 0 ? s0 : 1.0f, z == 2 ? 2 : 0, blockIdx.x, blockIdx.y);
}

// out projection + fused residual: AOut = attn@Wo^T + x (mode 3)
__global__ __launch_bounds__(256) void gemm_o(const __bf16* __restrict__ A,
                                              const __bf16* __restrict__ B,
                                              float* __restrict__ C,
                                              const float* __restrict__ x) {
  gemm_body<64>(A, B, C, 1.0f, 3, blockIdx.x, blockIdx.y, x);
}

// ---------------- transposed flash attention, LDS double-buffer, 1 barrier/tile --
// Round-6 math unchanged (KVBLK=64, S^T = K.Q^T, packed mask, exp2-domain softmax,
// one-tile-ahead reg prefetch). NEW: Ks/Vts double-buffered; per tile:
//   compute(buf[t&1]) ; ds_write buf[(t+1)&1] <- regs ; issue loads t+2 ; barrier
// Write of buf[(t+1)&1] is safe: its prior readers (tile t-1 compute) finished
// before the end-of-(t-1) barrier; visibility to tile t+1 via end-of-t barrier.
__global__ __launch_bounds__(256) void attn_kernel(
    const __bf16* __restrict__ Q, const __bf16* __restrict__ K,
    const __bf16* __restrict__ Vt, const float* __restrict__ bias,
    const u64* __restrict__ mp, __bf16* __restrict__ Aout) {
  __shared__ alignas(16) __bf16 Ks[2][64][72];    // kv x dh
  __shared__ alignas(16) __bf16 Vts[2][64][72];   // d x kv
  __shared__ alignas(16) __bf16 Ps[4][16][72];    // per-wave P[q][kv]
  const int tid = threadIdx.x;
  const int lane = tid & 63;
  const int wave = tid >> 6;
  const int h = blockIdx.y;
  const int q0 = blockIdx.x * 64 + wave * 16;
  const int g = lane >> 4, r16 = lane & 15;
  const int myq = q0 + r16;
  const int srow = tid >> 2;

  // Q as B-fragment: B[k=dh=g*8+j][n=q=r16]
  bf16x8 qf[2];
#pragma unroll
  for (int c = 0; c < 2; ++c)
    qf[c] = *(const bf16x8*)&Q[(long)myq * DD + h * DHD + c * 32 + g * 8];

  const float* bp = &bias[(long)myq * HSN + h * SS];
  const u64* mrow_p = &mp[(long)myq * (SS / 64)];

  f32x4 o[4] = {};                 // o[db][i]: O^T[d = db*16+g*4+i][q=r16]
  float mrow = -__builtin_inff();  // per-lane (q = r16)
  float lsum = 0.f;

  bf16x8 kA[2], vA[2], kB[2], vB[2];
  float4 bvA[4], bvB[4];
  u64 mwA, mwB;

  auto loadKV = [&](int kv0, bf16x8 (&kr)[2], bf16x8 (&vr)[2]) {
#pragma unroll
    for (int it = 0; it < 2; ++it) {
      const int seg = (tid & 3) + it * 4;
      kr[it] = *(const bf16x8*)&K[(long)(kv0 + srow) * DD + h * DHD + seg * 8];
      vr[it] = *(const bf16x8*)&Vt[(long)(h * DHD + srow) * SS + kv0 + seg * 8];
    }
  };
  auto loadBM = [&](int kv0, float4 (&bv)[4], u64& mw) {
#pragma unroll
    for (int t = 0; t < 4; ++t) bv[t] = *(const float4*)&bp[kv0 + t * 16 + g * 4];
    mw = mrow_p[kv0 >> 6];
  };
  auto writeLDS = [&](int buf, const bf16x8 (&kr)[2], const bf16x8 (&vr)[2]) {
#pragma unroll
    for (int it = 0; it < 2; ++it) {
      const int seg8 = ((tid & 3) + it * 4) * 8;
      *(bf16x8*)&Ks[buf][srow][seg8] = kr[it];
      *(bf16x8*)&Vts[buf][srow][seg8] = vr[it];
    }
  };

  auto compute = [&](int buf, const float4 (&bv)[4], u64 mw) {
    // S^T = K.Q^T : 4 chunks of 16 kv
    f32x4 s[4];
#pragma unroll
    for (int t = 0; t < 4; ++t) {
      bf16x8 kf0 = *(const bf16x8*)&Ks[buf][t * 16 + r16][g * 8];
      bf16x8 kf1 = *(const bf16x8*)&Ks[buf][t * 16 + r16][32 + g * 8];
      f32x4 acc = {};
      acc = __builtin_amdgcn_mfma_f32_16x16x32_bf16(kf0, qf[0], acc, 0, 0, 0);
      s[t] = __builtin_amdgcn_mfma_f32_16x16x32_bf16(kf1, qf[1], acc, 0, 0, 0);
    }
    // masked biased logits (log2 domain); mask bits t*16+g*4+i of mw
    float sv[4][4];
#pragma unroll
    for (int t = 0; t < 4; ++t) {
      const u32 mb = (u32)(mw >> (t * 16 + g * 4));
      sv[t][0] = (mb & 1u) ? s[t][0] + bv[t].x * LOG2E : -1e38f;
      sv[t][1] = (mb & 2u) ? s[t][1] + bv[t].y * LOG2E : -1e38f;
      sv[t][2] = (mb & 4u) ? s[t][2] + bv[t].z * LOG2E : -1e38f;
      sv[t][3] = (mb & 8u) ? s[t][3] + bv[t].w * LOG2E : -1e38f;
    }
    // online softmax for q = r16
    float m4 = -1e38f;
#pragma unroll
    for (int t = 0; t < 4; ++t)
#pragma unroll
      for (int i = 0; i < 4; ++i) m4 = fmaxf(m4, sv[t][i]);
    m4 = fmaxf(m4, __shfl_xor(m4, 16));
    m4 = fmaxf(m4, __shfl_xor(m4, 32));
    const float mnew = fmaxf(mrow, m4);
    const float alpha = exp2f(mrow - mnew);
    float ps = 0.f;
    float p[4][4];
#pragma unroll
    for (int t = 0; t < 4; ++t)
#pragma unroll
      for (int i = 0; i < 4; ++i) {
        p[t][i] = exp2f(sv[t][i] - mnew);
        ps += p[t][i];
      }
    ps += __shfl_xor(ps, 16);
    ps += __shfl_xor(ps, 32);
    lsum = lsum * alpha + ps;
    mrow = mnew;
#pragma unroll
    for (int db = 0; db < 4; ++db) o[db] *= alpha;
    // store P^T as P[q][kv] (8B contiguous over i)
#pragma unroll
    for (int t = 0; t < 4; ++t) {
      bf16x4 pb;
#pragma unroll
      for (int i = 0; i < 4; ++i) pb[i] = (__bf16)p[t][i];
      *(bf16x4*)&Ps[wave][r16][t * 16 + g * 4] = pb;
    }
    // O^T += V^T . P^T : two 32-kv halves
#pragma unroll
    for (int kh = 0; kh < 2; ++kh) {
      bf16x8 pf = *(const bf16x8*)&Ps[wave][r16][kh * 32 + g * 8];
#pragma unroll
      for (int db = 0; db < 4; ++db) {
        bf16x8 vf = *(const bf16x8*)&Vts[buf][db * 16 + r16][kh * 32 + g * 8];
        o[db] = __builtin_amdgcn_mfma_f32_16x16x32_bf16(vf, pf, o[db], 0, 0, 0);
      }
    }
  };

  // prologue: tile0 -> buf0 (only fully-exposed staging); tile1 -> regs B
  loadKV(0, kA, vA);
  loadBM(0, bvA, mwA);
  writeLDS(0, kA, vA);
  loadKV(64, kB, vB);
  loadBM(64, bvB, mwB);
  __syncthreads();

  for (int t2 = 0; t2 < SS; t2 += 128) {  // two tiles per iter: A-set even, B-set odd
    // even tile (t2): buf0
    compute(0, bvA, mwA);
    writeLDS(1, kB, vB);  // tile t2+64 -> buf1 (loads a full compute-phase old)
    {
      const int kvn = (t2 + 128 < SS) ? t2 + 128 : 0;  // clamp tail (harmless)
      loadKV(kvn, kA, vA);
      loadBM(kvn, bvA, mwA);
    }
    __syncthreads();
    // odd tile (t2+64): buf1
    compute(1, bvB, mwB);
    writeLDS(0, kA, vA);  // tile t2+128 -> buf0
    {
      const int kvn = (t2 + 192 < SS) ? t2 + 192 : 0;
      loadKV(kvn, kB, vB);
      loadBM(kvn, bvB, mwB);
    }
    __syncthreads();
  }

  const float rn = 1.f / lsum;
#pragma unroll
  for (int db = 0; db < 4; ++db) {
    bf16x4 r;
#pragma unroll
    for (int i = 0; i < 4; ++i) r[i] = (__bf16)(o[db][i] * rn);
    *(bf16x4*)&Aout[(long)myq * DD + h * DHD + db * 16 + g * 4] = r;
  }
}

// ---------------- LayerNorm (residual pre-added in gemm_o) ----------------
__global__ __launch_bounds__(256) void ln_kernel(const float* __restrict__ res,
                                                 const float* __restrict__ w,
                                                 const float* __restrict__ b,
                                                 float* __restrict__ out) {
  const long row = blockIdx.x;
  const int tid = threadIdx.x;
  const float4 a4 = ((const float4*)&res[row * DD])[tid];
  float v[4] = {a4.x, a4.y, a4.z, a4.w};
  float s = 0.f, s2 = 0.f;
#pragma unroll
  for (int j = 0; j < 4; ++j) { s += v[j]; s2 += v[j] * v[j]; }
#pragma unroll
  for (int off = 1; off < 64; off <<= 1) {
    s  += __shfl_xor(s, off);
    s2 += __shfl_xor(s2, off);
  }
  __shared__ float ss[4], ss2[4];
  if ((tid & 63) == 0) { ss[tid >> 6] = s; ss2[tid >> 6] = s2; }
  __syncthreads();
  s = ss[0] + ss[1] + ss[2] + ss[3];
  s2 = ss2[0] + ss2[1] + ss2[2] + ss2[3];
  const float mean = s * (1.f / DD);
  const float var = s2 * (1.f / DD) - mean * mean;
  const float inv = rsqrtf(var + 1e-5f);
  const float4 w4 = ((const float4*)w)[tid];
  const float4 b4 = ((const float4*)b)[tid];
  float4 o4;
  o4.x = (v[0] - mean) * inv * w4.x + b4.x;
  o4.y = (v[1] - mean) * inv * w4.y + b4.y;
  o4.z = (v[2] - mean) * inv * w4.z + b4.z;
  o4.w = (v[3] - mean) * inv * w4.w + b4.w;
  ((float4*)&out[row * DD])[tid] = o4;
}

// ---------------- host launch ----------------
extern "C" void kernel_launch(void* const* d_in, const int* in_sizes, int n_in,
                              void* d_out, int out_size, void* d_ws, size_t ws_size,
                              hipStream_t stream) {
  const float* x    = (const float*)d_in[0];
  const float* bias = (const float*)d_in[1];
  const int*   mask = (const int*)d_in[2];
  const float* Wq   = (const float*)d_in[3];
  const float* Wk   = (const float*)d_in[4];
  const float* Wv   = (const float*)d_in[5];
  const float* Wo   = (const float*)d_in[6];
  const float* lnw  = (const float*)d_in[7];
  const float* lnb  = (const float*)d_in[8];
  float* out = (float*)d_out;

  char* ws = (char*)d_ws;
  const size_t MB = 1024 * 1024;
  __bf16* xb   = (__bf16*)(ws + 0);
  __bf16* Wqb  = (__bf16*)(ws + 4 * MB);
  __bf16* Wkb  = (__bf16*)(ws + 6 * MB);
  __bf16* Wvb  = (__bf16*)(ws + 8 * MB);
  __bf16* Wob  = (__bf16*)(ws + 10 * MB);
  __bf16* Qb   = (__bf16*)(ws + 12 * MB);
  __bf16* Kb   = (__bf16*)(ws + 16 * MB);
  __bf16* Vtb  = (__bf16*)(ws + 24 * MB);
  __bf16* Atnb = (__bf16*)(ws + 28 * MB);
  float*  AOut = (float*)(ws + 32 * MB);
  u64*    mpk  = (u64*)(ws + 40 * MB);

  // fused converts + mask bit-pack (z: 0=x, 1..4=weights, 5=mask pack)
  cvt_all_kernel<<<dim3(SS * DD / 1024, 1, 6), dim3(256), 0, stream>>>(
      x, Wq, Wk, Wv, Wo, xb, Wqb, Wkb, Wvb, Wob, mask, mpk);

  // QKV projections (fused via grid.z); Q scaled by 0.125*log2(e); V written as V^T
  gemm_qkv<<<dim3(DD / 128, SS / 64, 3), dim3(256), 0, stream>>>(
      xb, Wqb, Wkb, Wvb, Qb, Kb, Vtb, 0.125f * LOG2E);

  // transposed flash attention, direct bf16 context output
  attn_kernel<<<dim3(SS / 64, HH), dim3(256), 0, stream>>>(Qb, Kb, Vtb, bias, mpk, Atnb);

  // out projection + fused residual (fp32 out)
  gemm_o<<<dim3(DD / 128, SS / 64), dim3(256), 0, stream>>>(Atnb, Wob, AOut, x);

  // LayerNorm
  ln_kernel<<<dim3(SS), dim3(256), 0, stream>>>(AOut, lnw, lnb, out);
}

// Round 8
// 477.753 us; speedup vs baseline: 1.0089x; 1.0089x over previous
//
#include <hip/hip_runtime.h>

#define SS 2048
#define DD 1024
#define HH 16
#define DHD 64
#define HSN (HH * SS)  // 32768
#define LOG2E 1.44269504088896340736f

typedef __bf16 bf16x8 __attribute__((ext_vector_type(8)));
typedef __bf16 bf16x4 __attribute__((ext_vector_type(4)));
typedef float f32x4 __attribute__((ext_vector_type(4)));
typedef unsigned int u32;
typedef unsigned long long u64;

__device__ __forceinline__ void glds16(const void* g, void* l) {
  __builtin_amdgcn_global_load_lds(
      (const __attribute__((address_space(1))) u32*)(const u32*)g,
      (__attribute__((address_space(3))) u32*)(u32*)l, 16, 0, 0);
}

// ------ fused fp32 -> bf16 converts (x, Wq, Wk, Wv, Wo) + mask bit-pack (z==5) ----
__global__ __launch_bounds__(256) void cvt_all_kernel(const float* __restrict__ x,
                                                      const float* __restrict__ Wq,
                                                      const float* __restrict__ Wk,
                                                      const float* __restrict__ Wv,
                                                      const float* __restrict__ Wo,
                                                      __bf16* xb, __bf16* Wqb, __bf16* Wkb,
                                                      __bf16* Wvb, __bf16* Wob,
                                                      const int* __restrict__ mask,
                                                      u64* __restrict__ mp) {
  const int z = blockIdx.z;
  if (z == 5) {  // mask bit-pack: 16 MB int32 -> 512 KB u64 (8 words per wave)
    const int wid = (blockIdx.x * 256 + threadIdx.x) >> 6;  // 8192 waves
    const int lane = threadIdx.x & 63;
#pragma unroll
    for (int w = 0; w < 8; ++w) {
      const long word = (long)wid * 8 + w;
      const u64 b = __ballot(mask[word * 64 + lane] != 0);
      if (lane == 0) mp[word] = b;
    }
    return;
  }
  const int n4 = (z == 0 ? SS * DD : DD * DD) / 4;
  const int i = blockIdx.x * 256 + threadIdx.x;
  if (i >= n4) return;
  const float* in = z == 0 ? x : (z == 1 ? Wq : (z == 2 ? Wk : (z == 3 ? Wv : Wo)));
  __bf16* out = z == 0 ? xb : (z == 1 ? Wqb : (z == 2 ? Wkb : (z == 3 ? Wvb : Wob)));
  const float4 v = ((const float4*)in)[i];
  bf16x4 r;
  r[0] = (__bf16)v.x; r[1] = (__bf16)v.y; r[2] = (__bf16)v.z; r[3] = (__bf16)v.w;
  *(bf16x4*)&out[(long)i * 4] = r;
}

// ---------------- NT GEMM body (m97 single-buffer, proven structure) ----
// C = A[M,K] * B[N,K]^T. BM in {64,128}, BN=128, BK=32.
// mode 0: bf16 out; mode 1: f32 out; mode 2: bf16 transposed out (V^T);
// mode 3: f32 out with fused residual add (Cout = acc + Xres).
template <int BM>
__device__ __forceinline__ void gemm_body(const __bf16* __restrict__ A,
                                          const __bf16* __restrict__ B,
                                          void* __restrict__ Cout, float scale, int mode,
                                          int bx, int by,
                                          const float* __restrict__ Xres = nullptr) {
  constexpr int MR = BM / 32;  // acc rows per wave
  __shared__ alignas(16) __bf16 As[BM * 32];
  __shared__ alignas(16) __bf16 Bs[128 * 32];
  const int tid = threadIdx.x;
  const int lane = tid & 63;
  const int wave = tid >> 6;
  const long m0 = (long)by * BM;
  const long n0 = (long)bx * 128;
  const int wm = (wave >> 1) * (BM / 2);
  const int wn = (wave & 1) * 64;
  const int g = lane >> 4, r16 = lane & 15;
  const int srow = tid >> 2, sseg = (tid & 3) * 8;

  f32x4 acc[MR][4] = {};

  for (int k0 = 0; k0 < DD; k0 += 32) {
#pragma unroll
    for (int it = 0; it < 2; ++it) {
      const int row = srow + it * 64;
      glds16(&B[(n0 + row) * DD + k0 + sseg], &Bs[row * 32 + sseg]);
    }
#pragma unroll
    for (int it = 0; it < BM / 64; ++it) {
      const int row = srow + it * 64;
      glds16(&A[(m0 + row) * DD + k0 + sseg], &As[row * 32 + sseg]);
    }
    __syncthreads();
    bf16x8 af[MR], bfr[4];
#pragma unroll
    for (int r = 0; r < MR; ++r) af[r] = *(const bf16x8*)&As[(wm + r * 16 + r16) * 32 + g * 8];
#pragma unroll
    for (int c = 0; c < 4; ++c) bfr[c] = *(const bf16x8*)&Bs[(wn + c * 16 + r16) * 32 + g * 8];
#pragma unroll
    for (int r = 0; r < MR; ++r)
#pragma unroll
      for (int c = 0; c < 4; ++c)
        acc[r][c] = __builtin_amdgcn_mfma_f32_16x16x32_bf16(af[r], bfr[c], acc[r][c], 0, 0, 0);
    __syncthreads();
  }

  if (mode == 2) {  // transposed bf16 store (V^T): 8B contiguous over i (rows)
#pragma unroll
    for (int r = 0; r < MR; ++r)
#pragma unroll
      for (int c = 0; c < 4; ++c) {
        const long row0 = m0 + wm + r * 16 + g * 4;
        const long col = n0 + wn + c * 16 + r16;
        bf16x4 rv;
#pragma unroll
        for (int i = 0; i < 4; ++i) rv[i] = (__bf16)(acc[r][c][i] * scale);
        *(bf16x4*)&((__bf16*)Cout)[col * SS + row0] = rv;
      }
  } else {
#pragma unroll
    for (int r = 0; r < MR; ++r)
#pragma unroll
      for (int c = 0; c < 4; ++c)
#pragma unroll
        for (int i = 0; i < 4; ++i) {
          const long row = m0 + wm + r * 16 + g * 4 + i;
          const long col = n0 + wn + c * 16 + r16;
          float v = acc[r][c][i] * scale;
          if (mode == 3) v += Xres[row * DD + col];
          if (mode != 0) ((float*)Cout)[row * DD + col] = v;
          else           ((__bf16*)Cout)[row * DD + col] = (__bf16)v;
        }
  }
}

// QKV projections: BM=64 -> grid (8,32,3) = 768 blocks = 3/CU.
__global__ __launch_bounds__(256) void gemm_qkv(const __bf16* __restrict__ A,
                                                const __bf16* __restrict__ B0,
                                                const __bf16* __restrict__ B1,
                                                const __bf16* __restrict__ B2,
                                                __bf16* C0, __bf16* C1, __bf16* C2,
                                                float s0) {
  const int z = blockIdx.z;
  const __bf16* B = z == 0 ? B0 : (z == 1 ? B1 : B2);
  __bf16* C = z == 0 ? C0 : (z == 1 ? C1 : C2);
  // z==2 writes V^T directly (mode 2) -> no separate transpose kernel
  gemm_body<64>(A, B, C, z == 0 ? s0 : 1.0f, z == 2 ? 2 : 0, blockIdx.x, blockIdx.y);
}

// out projection + fused residual: AOut = attn@Wo^T + x (mode 3)
__global__ __launch_bounds__(256) void gemm_o(const __bf16* __restrict__ A,
                                              const __bf16* __restrict__ B,
                                              float* __restrict__ C,
                                              const float* __restrict__ x) {
  gemm_body<64>(A, B, C, 1.0f, 3, blockIdx.x, blockIdx.y, x);
}

// ---------------- transposed flash attention (round-6 winner, verbatim) ----------
// KVBLK=64, single-buffer Ks/Vts, 2 barriers/tile, one-tile-ahead reg prefetch
// (T14). S^T = K.Q^T; packed mask; exp2-domain softmax; O^T = V^T . P^T.
__global__ __launch_bounds__(256) void attn_kernel(
    const __bf16* __restrict__ Q, const __bf16* __restrict__ K,
    const __bf16* __restrict__ Vt, const float* __restrict__ bias,
    const u64* __restrict__ mp, __bf16* __restrict__ Aout) {
  __shared__ alignas(16) __bf16 Ks[64][72];    // kv x dh
  __shared__ alignas(16) __bf16 Vts[64][72];   // d x kv
  __shared__ alignas(16) __bf16 Ps[4][16][72]; // per-wave P[q][kv]
  const int tid = threadIdx.x;
  const int lane = tid & 63;
  const int wave = tid >> 6;
  const int h = blockIdx.y;
  const int q0 = blockIdx.x * 64 + wave * 16;
  const int g = lane >> 4, r16 = lane & 15;
  const int myq = q0 + r16;
  const int srow = tid >> 2;

  // Q as B-fragment: B[k=dh=g*8+j][n=q=r16]
  bf16x8 qf[2];
#pragma unroll
  for (int c = 0; c < 2; ++c)
    qf[c] = *(const bf16x8*)&Q[(long)myq * DD + h * DHD + c * 32 + g * 8];

  const float* bp = &bias[(long)myq * HSN + h * SS];
  const u64* mrow_p = &mp[(long)myq * (SS / 64)];

  f32x4 o[4] = {};                 // o[db][i]: O^T[d = db*16+g*4+i][q=r16]
  float mrow = -__builtin_inff();  // per-lane (q = r16)
  float lsum = 0.f;

  bf16x8 kreg[2], vreg[2];
  float4 bvA[4], bvB[4];
  u64 mwA, mwB;

  auto loadKV = [&](int kv0) {
#pragma unroll
    for (int it = 0; it < 2; ++it) {
      const int seg = (tid & 3) + it * 4;
      kreg[it] = *(const bf16x8*)&K[(long)(kv0 + srow) * DD + h * DHD + seg * 8];
      vreg[it] = *(const bf16x8*)&Vt[(long)(h * DHD + srow) * SS + kv0 + seg * 8];
    }
  };
  auto loadBM = [&](int kv0, float4 (&bv)[4], u64& mw) {
#pragma unroll
    for (int t = 0; t < 4; ++t) bv[t] = *(const float4*)&bp[kv0 + t * 16 + g * 4];
    mw = mrow_p[kv0 >> 6];
  };

  auto tile = [&](int kvt, const float4 (&bvC)[4], u64 mwC,
                  float4 (&bvN)[4], u64& mwN) {
    __syncthreads();  // previous compute done reading Ks/Vts
#pragma unroll
    for (int it = 0; it < 2; ++it) {
      const int seg8 = ((tid & 3) + it * 4) * 8;
      *(bf16x8*)&Ks[srow][seg8] = kreg[it];
      *(bf16x8*)&Vts[srow][seg8] = vreg[it];
    }
    const int kvn = (kvt + 64 < SS) ? kvt + 64 : 0;  // clamp on last tile
    loadKV(kvn);            // next-tile K/V: HBM latency hides under this compute
    loadBM(kvn, bvN, mwN);  // next-tile bias/mask
    __syncthreads();  // LDS writes visible

    // S^T = K.Q^T : 4 chunks of 16 kv
    f32x4 s[4];
#pragma unroll
    for (int t = 0; t < 4; ++t) {
      bf16x8 kf0 = *(const bf16x8*)&Ks[t * 16 + r16][g * 8];
      bf16x8 kf1 = *(const bf16x8*)&Ks[t * 16 + r16][32 + g * 8];
      f32x4 acc = {};
      acc = __builtin_amdgcn_mfma_f32_16x16x32_bf16(kf0, qf[0], acc, 0, 0, 0);
      s[t] = __builtin_amdgcn_mfma_f32_16x16x32_bf16(kf1, qf[1], acc, 0, 0, 0);
    }

    // masked biased logits (log2 domain); mask bits t*16+g*4+i of mwC
    float sv[4][4];
#pragma unroll
    for (int t = 0; t < 4; ++t) {
      const u32 mb = (u32)(mwC >> (t * 16 + g * 4));
      sv[t][0] = (mb & 1u) ? s[t][0] + bvC[t].x * LOG2E : -1e38f;
      sv[t][1] = (mb & 2u) ? s[t][1] + bvC[t].y * LOG2E : -1e38f;
      sv[t][2] = (mb & 4u) ? s[t][2] + bvC[t].z * LOG2E : -1e38f;
      sv[t][3] = (mb & 8u) ? s[t][3] + bvC[t].w * LOG2E : -1e38f;
    }

    // online softmax for q = r16: local reduce over 16 regs + 2 shuffles
    float m4 = -1e38f;
#pragma unroll
    for (int t = 0; t < 4; ++t)
#pragma unroll
      for (int i = 0; i < 4; ++i) m4 = fmaxf(m4, sv[t][i]);
    m4 = fmaxf(m4, __shfl_xor(m4, 16));
    m4 = fmaxf(m4, __shfl_xor(m4, 32));
    const float mnew = fmaxf(mrow, m4);
    const float alpha = exp2f(mrow - mnew);
    float ps = 0.f;
    float p[4][4];
#pragma unroll
    for (int t = 0; t < 4; ++t)
#pragma unroll
      for (int i = 0; i < 4; ++i) {
        p[t][i] = exp2f(sv[t][i] - mnew);
        ps += p[t][i];
      }
    ps += __shfl_xor(ps, 16);
    ps += __shfl_xor(ps, 32);
    lsum = lsum * alpha + ps;
    mrow = mnew;
#pragma unroll
    for (int db = 0; db < 4; ++db) o[db] *= alpha;

    // store P^T as P[q][kv] (8B contiguous over i)
#pragma unroll
    for (int t = 0; t < 4; ++t) {
      bf16x4 pb;
#pragma unroll
      for (int i = 0; i < 4; ++i) pb[i] = (__bf16)p[t][i];
      *(bf16x4*)&Ps[wave][r16][t * 16 + g * 4] = pb;
    }

    // O^T += V^T . P^T : two 32-kv halves
#pragma unroll
    for (int kh = 0; kh < 2; ++kh) {
      bf16x8 pf = *(const bf16x8*)&Ps[wave][r16][kh * 32 + g * 8];
#pragma unroll
      for (int db = 0; db < 4; ++db) {
        bf16x8 vf = *(const bf16x8*)&Vts[db * 16 + r16][kh * 32 + g * 8];
        o[db] = __builtin_amdgcn_mfma_f32_16x16x32_bf16(vf, pf, o[db], 0, 0, 0);
      }
    }
  };

  loadKV(0);
  loadBM(0, bvA, mwA);
  for (int kv0 = 0; kv0 < SS; kv0 += 128) {  // 2x unroll: ping-pong reg sets
    tile(kv0, bvA, mwA, bvB, mwB);
    tile(kv0 + 64, bvB, mwB, bvA, mwA);
  }

  const float rn = 1.f / lsum;
#pragma unroll
  for (int db = 0; db < 4; ++db) {
    bf16x4 r;
#pragma unroll
    for (int i = 0; i < 4; ++i) r[i] = (__bf16)(o[db][i] * rn);
    *(bf16x4*)&Aout[(long)myq * DD + h * DHD + db * 16 + g * 4] = r;
  }
}

// ---------------- LayerNorm (residual pre-added in gemm_o) ----------------
__global__ __launch_bounds__(256) void ln_kernel(const float* __restrict__ res,
                                                 const float* __restrict__ w,
                                                 const float* __restrict__ b,
                                                 float* __restrict__ out) {
  const long row = blockIdx.x;
  const int tid = threadIdx.x;
  const float4 a4 = ((const float4*)&res[row * DD])[tid];
  float v[4] = {a4.x, a4.y, a4.z, a4.w};
  float s = 0.f, s2 = 0.f;
#pragma unroll
  for (int j = 0; j < 4; ++j) { s += v[j]; s2 += v[j] * v[j]; }
#pragma unroll
  for (int off = 1; off < 64; off <<= 1) {
    s  += __shfl_xor(s, off);
    s2 += __shfl_xor(s2, off);
  }
  __shared__ float ss[4], ss2[4];
  if ((tid & 63) == 0) { ss[tid >> 6] = s; ss2[tid >> 6] = s2; }
  __syncthreads();
  s = ss[0] + ss[1] + ss[2] + ss[3];
  s2 = ss2[0] + ss2[1] + ss2[2] + ss2[3];
  const float mean = s * (1.f / DD);
  const float var = s2 * (1.f / DD) - mean * mean;
  const float inv = rsqrtf(var + 1e-5f);
  const float4 w4 = ((const float4*)w)[tid];
  const float4 b4 = ((const float4*)b)[tid];
  float4 o4;
  o4.x = (v[0] - mean) * inv * w4.x + b4.x;
  o4.y = (v[1] - mean) * inv * w4.y + b4.y;
  o4.z = (v[2] - mean) * inv * w4.z + b4.z;
  o4.w = (v[3] - mean) * inv * w4.w + b4.w;
  ((float4*)&out[row * DD])[tid] = o4;
}

// ---------------- host launch ----------------
extern "C" void kernel_launch(void* const* d_in, const int* in_sizes, int n_in,
                              void* d_out, int out_size, void* d_ws, size_t ws_size,
                              hipStream_t stream) {
  const float* x    = (const float*)d_in[0];
  const float* bias = (const float*)d_in[1];
  const int*   mask = (const int*)d_in[2];
  const float* Wq   = (const float*)d_in[3];
  const float* Wk   = (const float*)d_in[4];
  const float* Wv   = (const float*)d_in[5];
  const float* Wo   = (const float*)d_in[6];
  const float* lnw  = (const float*)d_in[7];
  const float* lnb  = (const float*)d_in[8];
  float* out = (float*)d_out;

  char* ws = (char*)d_ws;
  const size_t MB = 1024 * 1024;
  __bf16* xb   = (__bf16*)(ws + 0);
  __bf16* Wqb  = (__bf16*)(ws + 4 * MB);
  __bf16* Wkb  = (__bf16*)(ws + 6 * MB);
  __bf16* Wvb  = (__bf16*)(ws + 8 * MB);
  __bf16* Wob  = (__bf16*)(ws + 10 * MB);
  __bf16* Qb   = (__bf16*)(ws + 12 * MB);
  __bf16* Kb   = (__bf16*)(ws + 16 * MB);
  __bf16* Vtb  = (__bf16*)(ws + 24 * MB);
  __bf16* Atnb = (__bf16*)(ws + 28 * MB);
  float*  AOut = (float*)(ws + 32 * MB);
  u64*    mpk  = (u64*)(ws + 40 * MB);

  // fused converts + mask bit-pack (z: 0=x, 1..4=weights, 5=mask pack)
  cvt_all_kernel<<<dim3(SS * DD / 1024, 1, 6), dim3(256), 0, stream>>>(
      x, Wq, Wk, Wv, Wo, xb, Wqb, Wkb, Wvb, Wob, mask, mpk);

  // QKV projections (fused via grid.z); Q scaled by 0.125*log2(e); V written as V^T
  gemm_qkv<<<dim3(DD / 128, SS / 64, 3), dim3(256), 0, stream>>>(
      xb, Wqb, Wkb, Wvb, Qb, Kb, Vtb, 0.125f * LOG2E);

  // transposed flash attention, direct bf16 context output
  attn_kernel<<<dim3(SS / 64, HH), dim3(256), 0, stream>>>(Qb, Kb, Vtb, bias, mpk, Atnb);

  // out projection + fused residual (fp32 out)
  gemm_o<<<dim3(DD / 128, SS / 64), dim3(256), 0, stream>>>(Atnb, Wob, AOut, x);

  // LayerNorm
  ln_kernel<<<dim3(SS), dim3(256), 0, stream>>>(AOut, lnw, lnb, out);
}